// Round 4
// baseline (423.767 us; speedup 1.0000x reference)
//
#include <hip/hip_runtime.h>

#define H_ 160
#define W_ 160
#define CIN 32
#define COUT 32
#define HW_ (H_ * W_)
#define NPIX (8 * HW_)   // 204800 pixels total

// ============================================================================
// R4: K-split parallelism + XCD-locality swizzle.
//  - dcn_offset: 2 threads/pixel (16 channels each), shuffle-reduce over xor 32.
//  - dcn_sample: 4 threads/pixel (8 channels each), shuffle-reduce xor 16+32.
//  - blockIdx swizzled so XCD k sees exactly image k (x slice 3.3MB fits 4MB L2).
//  - all accumulators are named scalars (R1/R2: array demotion -> 5GB scratch).
// ============================================================================

// ---------------- Kernel A: 3x3 offset conv (Cin=32 -> 18 channels) --------
// block = 256 threads = 128 pixels x 2 channel-halves.
// wave layout: sub = lane>>5, pixel = wave*32 + (lane&31)  -> reduce xor 32.
__global__ __launch_bounds__(256, 4) void dcn_offset(
    const float* __restrict__ x,      // (8, 32, 160, 160)
    const float* __restrict__ w_off,  // (18, 32, 3, 3)
    const float* __restrict__ b_off,  // (18,)
    float* __restrict__ off_ws)       // [18][NPIX]
{
    __shared__ __align__(16) float wl[9 * 32 * 20];  // [tap][c][j], j padded to 20
    __shared__ float bl[18];
    const int tid = threadIdx.x;
    for (int d = tid; d < 9 * 32 * 20; d += 256) {
        int tap = d / 640, c = (d / 20) % 32, j = d % 20;
        wl[d] = (j < 18) ? w_off[(j * 32 + c) * 9 + tap] : 0.0f;
    }
    if (tid < 18) bl[tid] = b_off[tid];
    __syncthreads();

    // XCD swizzle: 1600 blocks, XCD k <- blocks [k*200, (k+1)*200) = image k
    const int blk = (blockIdx.x & 7) * 200 + (blockIdx.x >> 3);
    const int lane = tid & 63;
    const int sub = lane >> 5;                       // 0..1, channels sub*16..
    const int pl = (tid >> 6) * 32 + (lane & 31);    // 0..127
    const int pix = blk * 128 + pl;
    const int w = pix % W_;
    const int h = (pix / W_) % H_;
    const int b = pix / HW_;
    const float* __restrict__ xb = x + (size_t)b * CIN * HW_ + (size_t)(sub * 16) * HW_;

    float a0 = 0, a1 = 0, a2 = 0, a3 = 0, a4 = 0, a5 = 0, a6 = 0, a7 = 0, a8 = 0;
    float a9 = 0, a10 = 0, a11 = 0, a12 = 0, a13 = 0, a14 = 0, a15 = 0, a16 = 0, a17 = 0;

    for (int tap = 0; tap < 9; ++tap) {
        const int yy = h - 1 + tap / 3;
        const int xx = w - 1 + tap % 3;
        const bool valid = (yy >= 0) && (yy < H_) && (xx >= 0) && (xx < W_);
        const int idx = valid ? (yy * W_ + xx) : 0;
        const float* __restrict__ wt = &wl[tap * 640 + sub * 16 * 20];
        #pragma unroll 2
        for (int cc = 0; cc < 16; ++cc) {
            const float xv = valid ? xb[cc * HW_ + idx] : 0.0f;
            const float* __restrict__ wc = wt + cc * 20;
            float4 q;
            q = *(const float4*)(wc);
            a0 = fmaf(xv, q.x, a0);  a1 = fmaf(xv, q.y, a1);
            a2 = fmaf(xv, q.z, a2);  a3 = fmaf(xv, q.w, a3);
            q = *(const float4*)(wc + 4);
            a4 = fmaf(xv, q.x, a4);  a5 = fmaf(xv, q.y, a5);
            a6 = fmaf(xv, q.z, a6);  a7 = fmaf(xv, q.w, a7);
            q = *(const float4*)(wc + 8);
            a8 = fmaf(xv, q.x, a8);  a9 = fmaf(xv, q.y, a9);
            a10 = fmaf(xv, q.z, a10); a11 = fmaf(xv, q.w, a11);
            q = *(const float4*)(wc + 12);
            a12 = fmaf(xv, q.x, a12); a13 = fmaf(xv, q.y, a13);
            a14 = fmaf(xv, q.z, a14); a15 = fmaf(xv, q.w, a15);
            const float2 q2 = *(const float2*)(wc + 16);
            a16 = fmaf(xv, q2.x, a16); a17 = fmaf(xv, q2.y, a17);
        }
    }

    // combine the two channel-halves (partner lane = lane ^ 32)
    a0  += __shfl_xor(a0, 32);  a1  += __shfl_xor(a1, 32);
    a2  += __shfl_xor(a2, 32);  a3  += __shfl_xor(a3, 32);
    a4  += __shfl_xor(a4, 32);  a5  += __shfl_xor(a5, 32);
    a6  += __shfl_xor(a6, 32);  a7  += __shfl_xor(a7, 32);
    a8  += __shfl_xor(a8, 32);  a9  += __shfl_xor(a9, 32);
    a10 += __shfl_xor(a10, 32); a11 += __shfl_xor(a11, 32);
    a12 += __shfl_xor(a12, 32); a13 += __shfl_xor(a13, 32);
    a14 += __shfl_xor(a14, 32); a15 += __shfl_xor(a15, 32);
    a16 += __shfl_xor(a16, 32); a17 += __shfl_xor(a17, 32);

    if (sub == 0) {
        off_ws[0 * NPIX + pix] = a0 + bl[0];
        off_ws[1 * NPIX + pix] = a1 + bl[1];
        off_ws[2 * NPIX + pix] = a2 + bl[2];
        off_ws[3 * NPIX + pix] = a3 + bl[3];
        off_ws[4 * NPIX + pix] = a4 + bl[4];
        off_ws[5 * NPIX + pix] = a5 + bl[5];
        off_ws[6 * NPIX + pix] = a6 + bl[6];
        off_ws[7 * NPIX + pix] = a7 + bl[7];
        off_ws[8 * NPIX + pix] = a8 + bl[8];
    } else {
        off_ws[ 9 * NPIX + pix] = a9  + bl[9];
        off_ws[10 * NPIX + pix] = a10 + bl[10];
        off_ws[11 * NPIX + pix] = a11 + bl[11];
        off_ws[12 * NPIX + pix] = a12 + bl[12];
        off_ws[13 * NPIX + pix] = a13 + bl[13];
        off_ws[14 * NPIX + pix] = a14 + bl[14];
        off_ws[15 * NPIX + pix] = a15 + bl[15];
        off_ws[16 * NPIX + pix] = a16 + bl[16];
        off_ws[17 * NPIX + pix] = a17 + bl[17];
    }
}

// ------ Kernel B: bilinear deformable sampling + 32-ch matmul + ReLU --------
// block = 256 threads = 64 pixels x 4 channel-quarters.
// wave layout: sub = lane>>4, pixel = wave*16 + (lane&15) -> reduce xor 16,32.
// weight LDS: [tap][sub-region(260)] with +4 pad so the 4 subs' broadcast
// addresses land on distinct banks (unpadded stride 8*32*4B = bank-aligned ->
// 4-way conflict = 1.58x per m136).
__global__ __launch_bounds__(256, 4) void dcn_sample(
    const float* __restrict__ x,       // (8, 32, 160, 160)
    const float* __restrict__ w_dcn,   // (32, 32, 3, 3)
    const float* __restrict__ off_ws,  // [18][NPIX]
    float* __restrict__ out)           // (8, 32, 160, 160)
{
    __shared__ __align__(16) float wl[9 * (4 * 260)];  // 9360 floats = 37.4 KB
    const int tid = threadIdx.x;
    for (int d = tid; d < 9 * 1024; d += 256) {
        int tap = d >> 10, r = d & 1023;
        int sub = r >> 8, cc = (r >> 5) & 7, o = r & 31;
        wl[tap * 1040 + sub * 260 + cc * 32 + o] =
            w_dcn[(o * 32 + (sub * 8 + cc)) * 9 + tap];
    }
    __syncthreads();

    // XCD swizzle: 3200 blocks, XCD k <- blocks [k*400, (k+1)*400) = image k
    const int blk = (blockIdx.x & 7) * 400 + (blockIdx.x >> 3);
    const int lane = tid & 63;
    const int sub = lane >> 4;                       // 0..3, channels sub*8..
    const int pl = (tid >> 6) * 16 + (lane & 15);    // 0..63
    const int pix = blk * 64 + pl;
    const int w = pix % W_;
    const int h = (pix / W_) % H_;
    const int b = pix / HW_;
    const float* __restrict__ xb = x + (size_t)b * CIN * HW_ + (size_t)(sub * 8) * HW_;

    float s0 = 0, s1 = 0, s2 = 0, s3 = 0, s4 = 0, s5 = 0, s6 = 0, s7 = 0;
    float s8 = 0, s9 = 0, s10 = 0, s11 = 0, s12 = 0, s13 = 0, s14 = 0, s15 = 0;
    float s16 = 0, s17 = 0, s18 = 0, s19 = 0, s20 = 0, s21 = 0, s22 = 0, s23 = 0;
    float s24 = 0, s25 = 0, s26 = 0, s27 = 0, s28 = 0, s29 = 0, s30 = 0, s31 = 0;

    for (int tap = 0; tap < 9; ++tap) {
        const float dy = off_ws[(2 * tap) * NPIX + pix];
        const float dx = off_ws[(2 * tap + 1) * NPIX + pix];
        const float py = (float)(h - 1 + tap / 3) + dy;
        const float px = (float)(w - 1 + tap % 3) + dx;
        const float fy0 = floorf(py), fx0 = floorf(px);
        const float wy1 = py - fy0, wx1 = px - fx0;
        const float wy0 = 1.0f - wy1, wx0 = 1.0f - wx1;
        const int y0 = (int)fy0, x0 = (int)fx0;
        const int y1 = y0 + 1, x1 = x0 + 1;
        const bool vy0 = (y0 >= 0) && (y0 < H_);
        const bool vy1 = (y1 >= 0) && (y1 < H_);
        const bool vx0 = (x0 >= 0) && (x0 < W_);
        const bool vx1 = (x1 >= 0) && (x1 < W_);
        const float w00 = (vy0 && vx0) ? wy0 * wx0 : 0.0f;
        const float w01 = (vy0 && vx1) ? wy0 * wx1 : 0.0f;
        const float w10 = (vy1 && vx0) ? wy1 * wx0 : 0.0f;
        const float w11 = (vy1 && vx1) ? wy1 * wx1 : 0.0f;
        const int yc0 = min(max(y0, 0), H_ - 1), yc1 = min(max(y1, 0), H_ - 1);
        const int xc0 = min(max(x0, 0), W_ - 1), xc1 = min(max(x1, 0), W_ - 1);
        const int i00 = yc0 * W_ + xc0, i01 = yc0 * W_ + xc1;
        const int i10 = yc1 * W_ + xc0, i11 = yc1 * W_ + xc1;
        const float* __restrict__ wt = &wl[tap * 1040 + sub * 260];
        #pragma unroll 2
        for (int cc = 0; cc < 8; ++cc) {
            const float* __restrict__ xc = xb + cc * HW_;
            const float v = w00 * xc[i00] + w01 * xc[i01]
                          + w10 * xc[i10] + w11 * xc[i11];
            const float* __restrict__ wc = wt + (cc << 5);
            float4 q;
            q = *(const float4*)(wc);
            s0 = fmaf(v, q.x, s0);   s1 = fmaf(v, q.y, s1);
            s2 = fmaf(v, q.z, s2);   s3 = fmaf(v, q.w, s3);
            q = *(const float4*)(wc + 4);
            s4 = fmaf(v, q.x, s4);   s5 = fmaf(v, q.y, s5);
            s6 = fmaf(v, q.z, s6);   s7 = fmaf(v, q.w, s7);
            q = *(const float4*)(wc + 8);
            s8 = fmaf(v, q.x, s8);   s9 = fmaf(v, q.y, s9);
            s10 = fmaf(v, q.z, s10); s11 = fmaf(v, q.w, s11);
            q = *(const float4*)(wc + 12);
            s12 = fmaf(v, q.x, s12); s13 = fmaf(v, q.y, s13);
            s14 = fmaf(v, q.z, s14); s15 = fmaf(v, q.w, s15);
            q = *(const float4*)(wc + 16);
            s16 = fmaf(v, q.x, s16); s17 = fmaf(v, q.y, s17);
            s18 = fmaf(v, q.z, s18); s19 = fmaf(v, q.w, s19);
            q = *(const float4*)(wc + 20);
            s20 = fmaf(v, q.x, s20); s21 = fmaf(v, q.y, s21);
            s22 = fmaf(v, q.z, s22); s23 = fmaf(v, q.w, s23);
            q = *(const float4*)(wc + 24);
            s24 = fmaf(v, q.x, s24); s25 = fmaf(v, q.y, s25);
            s26 = fmaf(v, q.z, s26); s27 = fmaf(v, q.w, s27);
            q = *(const float4*)(wc + 28);
            s28 = fmaf(v, q.x, s28); s29 = fmaf(v, q.y, s29);
            s30 = fmaf(v, q.z, s30); s31 = fmaf(v, q.w, s31);
        }
    }

    // combine the 4 channel-quarters: butterfly over xor 16 then 32
    #define RED2(v) v += __shfl_xor(v, 16); v += __shfl_xor(v, 32)
    RED2(s0);  RED2(s1);  RED2(s2);  RED2(s3);
    RED2(s4);  RED2(s5);  RED2(s6);  RED2(s7);
    RED2(s8);  RED2(s9);  RED2(s10); RED2(s11);
    RED2(s12); RED2(s13); RED2(s14); RED2(s15);
    RED2(s16); RED2(s17); RED2(s18); RED2(s19);
    RED2(s20); RED2(s21); RED2(s22); RED2(s23);
    RED2(s24); RED2(s25); RED2(s26); RED2(s27);
    RED2(s28); RED2(s29); RED2(s30); RED2(s31);
    #undef RED2

    // each sub stores its 8 output channels (all lanes now hold full sums)
    float* __restrict__ ob = out + (size_t)b * COUT * HW_ + h * W_ + w;
    if (sub == 0) {
        ob[0 * HW_] = fmaxf(s0, 0.0f);  ob[1 * HW_] = fmaxf(s1, 0.0f);
        ob[2 * HW_] = fmaxf(s2, 0.0f);  ob[3 * HW_] = fmaxf(s3, 0.0f);
        ob[4 * HW_] = fmaxf(s4, 0.0f);  ob[5 * HW_] = fmaxf(s5, 0.0f);
        ob[6 * HW_] = fmaxf(s6, 0.0f);  ob[7 * HW_] = fmaxf(s7, 0.0f);
    } else if (sub == 1) {
        ob[ 8 * HW_] = fmaxf(s8, 0.0f);   ob[ 9 * HW_] = fmaxf(s9, 0.0f);
        ob[10 * HW_] = fmaxf(s10, 0.0f);  ob[11 * HW_] = fmaxf(s11, 0.0f);
        ob[12 * HW_] = fmaxf(s12, 0.0f);  ob[13 * HW_] = fmaxf(s13, 0.0f);
        ob[14 * HW_] = fmaxf(s14, 0.0f);  ob[15 * HW_] = fmaxf(s15, 0.0f);
    } else if (sub == 2) {
        ob[16 * HW_] = fmaxf(s16, 0.0f);  ob[17 * HW_] = fmaxf(s17, 0.0f);
        ob[18 * HW_] = fmaxf(s18, 0.0f);  ob[19 * HW_] = fmaxf(s19, 0.0f);
        ob[20 * HW_] = fmaxf(s20, 0.0f);  ob[21 * HW_] = fmaxf(s21, 0.0f);
        ob[22 * HW_] = fmaxf(s22, 0.0f);  ob[23 * HW_] = fmaxf(s23, 0.0f);
    } else {
        ob[24 * HW_] = fmaxf(s24, 0.0f);  ob[25 * HW_] = fmaxf(s25, 0.0f);
        ob[26 * HW_] = fmaxf(s26, 0.0f);  ob[27 * HW_] = fmaxf(s27, 0.0f);
        ob[28 * HW_] = fmaxf(s28, 0.0f);  ob[29 * HW_] = fmaxf(s29, 0.0f);
        ob[30 * HW_] = fmaxf(s30, 0.0f);  ob[31 * HW_] = fmaxf(s31, 0.0f);
    }
}

extern "C" void kernel_launch(void* const* d_in, const int* in_sizes, int n_in,
                              void* d_out, int out_size, void* d_ws, size_t ws_size,
                              hipStream_t stream) {
    const float* x     = (const float*)d_in[0];
    const float* w_off = (const float*)d_in[1];
    const float* b_off = (const float*)d_in[2];
    const float* w_dcn = (const float*)d_in[3];
    float* out    = (float*)d_out;
    float* off_ws = (float*)d_ws;   // needs 18*204800*4 = 14.75 MB

    dcn_offset<<<1600, 256, 0, stream>>>(x, w_off, b_off, off_ws);  // 128 pix/blk
    dcn_sample<<<3200, 256, 0, stream>>>(x, w_dcn, off_ws, out);    //  64 pix/blk
}

// Round 5
// 323.408 us; speedup vs baseline: 1.3103x; 1.3103x over previous
//
#include <hip/hip_runtime.h>

#define H_ 160
#define W_ 160
#define CIN 32
#define COUT 32
#define HW_ (H_ * W_)
#define NPIX (8 * HW_)   // 204800 pixels total

// ============================================================================
// R5: memory-level parallelism. R3/R4 were load-latency-bound (VALUBusy 23%,
// HBM idle): inner loops issued 1-2 loads then stalled ~200cy on L2. Fix:
// batch independent loads (9 tap loads per c-iter in offset; 16 corner loads
// per 4-channel group in sample) so latency hides behind the FMA burst.
// No private arrays anywhere (R1/R2: array demotion -> 5 GB scratch traffic).
// No XCD swizzle (R4: confining an image to one XCD's L2 slice cut gather BW).
// ============================================================================

// ---------------- Kernel A: 3x3 offset conv (Cin=32 -> 18 channels) --------
__global__ __launch_bounds__(256, 4) void dcn_offset(
    const float* __restrict__ x,      // (8, 32, 160, 160)
    const float* __restrict__ w_off,  // (18, 32, 3, 3)
    const float* __restrict__ b_off,  // (18,)
    float* __restrict__ off_ws)       // [18][NPIX]
{
    // LDS layout [c][tap][j(20)] -> per (c,tap) a contiguous 20-float row
    __shared__ __align__(16) float wl[32 * 9 * 20];
    __shared__ float bl[18];
    const int tid = threadIdx.x;
    for (int d = tid; d < 32 * 9 * 20; d += 256) {
        int c = d / 180, tap = (d / 20) % 9, j = d % 20;
        wl[d] = (j < 18) ? w_off[(j * 32 + c) * 9 + tap] : 0.0f;
    }
    if (tid < 18) bl[tid] = b_off[tid];
    __syncthreads();

    const int pix = blockIdx.x * 256 + tid;
    const int w = pix % W_;
    const int h = (pix / W_) % H_;
    const int b = pix / HW_;
    const float* __restrict__ xb = x + (size_t)b * CIN * HW_;

    // per-tap clamped indices + validity masks (named scalars)
    const int ym = max(h - 1, 0), yp = min(h + 1, H_ - 1);
    const int xm = max(w - 1, 0), xp = min(w + 1, W_ - 1);
    const float ry0 = (h - 1 >= 0) ? 1.0f : 0.0f;
    const float ry2 = (h + 1 < H_) ? 1.0f : 0.0f;
    const float cx0 = (w - 1 >= 0) ? 1.0f : 0.0f;
    const float cx2 = (w + 1 < W_) ? 1.0f : 0.0f;
    const int iA = ym * W_ + xm, iB = ym * W_ + w, iC = ym * W_ + xp;
    const int iD = h  * W_ + xm, iE = h  * W_ + w, iF = h  * W_ + xp;
    const int iG = yp * W_ + xm, iH = yp * W_ + w, iI = yp * W_ + xp;
    const float mA = ry0 * cx0, mB = ry0, mC = ry0 * cx2;
    const float mD = cx0,       mE = 1.f, mF = cx2;
    const float mG = ry2 * cx0, mH = ry2, mI = ry2 * cx2;

    float a0 = 0, a1 = 0, a2 = 0, a3 = 0, a4 = 0, a5 = 0, a6 = 0, a7 = 0, a8 = 0;
    float a9 = 0, a10 = 0, a11 = 0, a12 = 0, a13 = 0, a14 = 0, a15 = 0, a16 = 0, a17 = 0;

    #define OFFTAP(vt, wptr) { \
        float4 q; \
        q = *(const float4*)((wptr)); \
        a0 = fmaf((vt), q.x, a0);  a1 = fmaf((vt), q.y, a1); \
        a2 = fmaf((vt), q.z, a2);  a3 = fmaf((vt), q.w, a3); \
        q = *(const float4*)((wptr) + 4); \
        a4 = fmaf((vt), q.x, a4);  a5 = fmaf((vt), q.y, a5); \
        a6 = fmaf((vt), q.z, a6);  a7 = fmaf((vt), q.w, a7); \
        q = *(const float4*)((wptr) + 8); \
        a8 = fmaf((vt), q.x, a8);  a9 = fmaf((vt), q.y, a9); \
        a10 = fmaf((vt), q.z, a10); a11 = fmaf((vt), q.w, a11); \
        q = *(const float4*)((wptr) + 12); \
        a12 = fmaf((vt), q.x, a12); a13 = fmaf((vt), q.y, a13); \
        a14 = fmaf((vt), q.z, a14); a15 = fmaf((vt), q.w, a15); \
        q = *(const float4*)((wptr) + 16); \
        a16 = fmaf((vt), q.x, a16); a17 = fmaf((vt), q.y, a17); }

    #pragma unroll 2
    for (int c = 0; c < 32; ++c) {
        const float* __restrict__ xc = xb + c * HW_;
        // 9 independent loads issued together -> latency overlapped
        const float vA = xc[iA], vB = xc[iB], vC = xc[iC];
        const float vD = xc[iD], vE = xc[iE], vF = xc[iF];
        const float vG = xc[iG], vH = xc[iH], vI = xc[iI];
        const float* __restrict__ wc = &wl[c * 180];
        OFFTAP(vA * mA, wc);
        OFFTAP(vB * mB, wc + 20);
        OFFTAP(vC * mC, wc + 40);
        OFFTAP(vD * mD, wc + 60);
        OFFTAP(vE,      wc + 80);
        OFFTAP(vF * mF, wc + 100);
        OFFTAP(vG * mG, wc + 120);
        OFFTAP(vH * mH, wc + 140);
        OFFTAP(vI * mI, wc + 160);
    }
    #undef OFFTAP

    off_ws[ 0 * NPIX + pix] = a0  + bl[0];
    off_ws[ 1 * NPIX + pix] = a1  + bl[1];
    off_ws[ 2 * NPIX + pix] = a2  + bl[2];
    off_ws[ 3 * NPIX + pix] = a3  + bl[3];
    off_ws[ 4 * NPIX + pix] = a4  + bl[4];
    off_ws[ 5 * NPIX + pix] = a5  + bl[5];
    off_ws[ 6 * NPIX + pix] = a6  + bl[6];
    off_ws[ 7 * NPIX + pix] = a7  + bl[7];
    off_ws[ 8 * NPIX + pix] = a8  + bl[8];
    off_ws[ 9 * NPIX + pix] = a9  + bl[9];
    off_ws[10 * NPIX + pix] = a10 + bl[10];
    off_ws[11 * NPIX + pix] = a11 + bl[11];
    off_ws[12 * NPIX + pix] = a12 + bl[12];
    off_ws[13 * NPIX + pix] = a13 + bl[13];
    off_ws[14 * NPIX + pix] = a14 + bl[14];
    off_ws[15 * NPIX + pix] = a15 + bl[15];
    off_ws[16 * NPIX + pix] = a16 + bl[16];
    off_ws[17 * NPIX + pix] = a17 + bl[17];
}

// ------ Kernel B: bilinear deformable sampling + 32-ch matmul + ReLU --------
__global__ __launch_bounds__(256, 4) void dcn_sample(
    const float* __restrict__ x,       // (8, 32, 160, 160)
    const float* __restrict__ w_dcn,   // (32, 32, 3, 3)
    const float* __restrict__ off_ws,  // [18][NPIX]
    float* __restrict__ out)           // (8, 32, 160, 160)
{
    __shared__ __align__(16) float wl[9 * 32 * 32];  // [tap][c][o]
    const int tid = threadIdx.x;
    for (int d = tid; d < 9 * 1024; d += 256) {
        int tap = d >> 10, c = (d >> 5) & 31, o = d & 31;
        wl[d] = w_dcn[(o * 32 + c) * 9 + tap];
    }
    __syncthreads();

    const int pix = blockIdx.x * 256 + tid;
    const int w = pix % W_;
    const int h = (pix / W_) % H_;
    const int b = pix / HW_;
    const float* __restrict__ xb = x + (size_t)b * CIN * HW_;

    float s0 = 0, s1 = 0, s2 = 0, s3 = 0, s4 = 0, s5 = 0, s6 = 0, s7 = 0;
    float s8 = 0, s9 = 0, s10 = 0, s11 = 0, s12 = 0, s13 = 0, s14 = 0, s15 = 0;
    float s16 = 0, s17 = 0, s18 = 0, s19 = 0, s20 = 0, s21 = 0, s22 = 0, s23 = 0;
    float s24 = 0, s25 = 0, s26 = 0, s27 = 0, s28 = 0, s29 = 0, s30 = 0, s31 = 0;

    #define FMA32(v, wptr) { \
        float4 q; \
        q = *(const float4*)((wptr)); \
        s0 = fmaf((v), q.x, s0);   s1 = fmaf((v), q.y, s1); \
        s2 = fmaf((v), q.z, s2);   s3 = fmaf((v), q.w, s3); \
        q = *(const float4*)((wptr) + 4); \
        s4 = fmaf((v), q.x, s4);   s5 = fmaf((v), q.y, s5); \
        s6 = fmaf((v), q.z, s6);   s7 = fmaf((v), q.w, s7); \
        q = *(const float4*)((wptr) + 8); \
        s8 = fmaf((v), q.x, s8);   s9 = fmaf((v), q.y, s9); \
        s10 = fmaf((v), q.z, s10); s11 = fmaf((v), q.w, s11); \
        q = *(const float4*)((wptr) + 12); \
        s12 = fmaf((v), q.x, s12); s13 = fmaf((v), q.y, s13); \
        s14 = fmaf((v), q.z, s14); s15 = fmaf((v), q.w, s15); \
        q = *(const float4*)((wptr) + 16); \
        s16 = fmaf((v), q.x, s16); s17 = fmaf((v), q.y, s17); \
        s18 = fmaf((v), q.z, s18); s19 = fmaf((v), q.w, s19); \
        q = *(const float4*)((wptr) + 20); \
        s20 = fmaf((v), q.x, s20); s21 = fmaf((v), q.y, s21); \
        s22 = fmaf((v), q.z, s22); s23 = fmaf((v), q.w, s23); \
        q = *(const float4*)((wptr) + 24); \
        s24 = fmaf((v), q.x, s24); s25 = fmaf((v), q.y, s25); \
        s26 = fmaf((v), q.z, s26); s27 = fmaf((v), q.w, s27); \
        q = *(const float4*)((wptr) + 28); \
        s28 = fmaf((v), q.x, s28); s29 = fmaf((v), q.y, s29); \
        s30 = fmaf((v), q.z, s30); s31 = fmaf((v), q.w, s31); }

    #pragma unroll
    for (int tap = 0; tap < 9; ++tap) {
        const float dy = off_ws[(2 * tap) * NPIX + pix];
        const float dx = off_ws[(2 * tap + 1) * NPIX + pix];
        const float py = (float)(h - 1 + tap / 3) + dy;
        const float px = (float)(w - 1 + tap % 3) + dx;
        const float fy0 = floorf(py), fx0 = floorf(px);
        const float wy1 = py - fy0, wx1 = px - fx0;
        const float wy0 = 1.0f - wy1, wx0 = 1.0f - wx1;
        const int y0 = (int)fy0, x0 = (int)fx0;
        const int y1 = y0 + 1, x1 = x0 + 1;
        const bool vy0 = (y0 >= 0) && (y0 < H_);
        const bool vy1 = (y1 >= 0) && (y1 < H_);
        const bool vx0 = (x0 >= 0) && (x0 < W_);
        const bool vx1 = (x1 >= 0) && (x1 < W_);
        const float w00 = (vy0 && vx0) ? wy0 * wx0 : 0.0f;
        const float w01 = (vy0 && vx1) ? wy0 * wx1 : 0.0f;
        const float w10 = (vy1 && vx0) ? wy1 * wx0 : 0.0f;
        const float w11 = (vy1 && vx1) ? wy1 * wx1 : 0.0f;
        const int yc0 = min(max(y0, 0), H_ - 1), yc1 = min(max(y1, 0), H_ - 1);
        const int xc0 = min(max(x0, 0), W_ - 1), xc1 = min(max(x1, 0), W_ - 1);
        const int i00 = yc0 * W_ + xc0, i01 = yc0 * W_ + xc1;
        const int i10 = yc1 * W_ + xc0, i11 = yc1 * W_ + xc1;
        const float* __restrict__ wt = &wl[tap * 1024];

        for (int c = 0; c < 32; c += 4) {
            // 16 independent gather loads issued together
            const float* __restrict__ p0 = xb + (c + 0) * HW_;
            const float* __restrict__ p1 = xb + (c + 1) * HW_;
            const float* __restrict__ p2 = xb + (c + 2) * HW_;
            const float* __restrict__ p3 = xb + (c + 3) * HW_;
            const float a0_ = p0[i00], b0_ = p0[i01], c0_ = p0[i10], d0_ = p0[i11];
            const float a1_ = p1[i00], b1_ = p1[i01], c1_ = p1[i10], d1_ = p1[i11];
            const float a2_ = p2[i00], b2_ = p2[i01], c2_ = p2[i10], d2_ = p2[i11];
            const float a3_ = p3[i00], b3_ = p3[i01], c3_ = p3[i10], d3_ = p3[i11];
            const float v0 = fmaf(w00, a0_, fmaf(w01, b0_, fmaf(w10, c0_, w11 * d0_)));
            const float v1 = fmaf(w00, a1_, fmaf(w01, b1_, fmaf(w10, c1_, w11 * d1_)));
            const float v2 = fmaf(w00, a2_, fmaf(w01, b2_, fmaf(w10, c2_, w11 * d2_)));
            const float v3 = fmaf(w00, a3_, fmaf(w01, b3_, fmaf(w10, c3_, w11 * d3_)));
            FMA32(v0, wt + ((c + 0) << 5));
            FMA32(v1, wt + ((c + 1) << 5));
            FMA32(v2, wt + ((c + 2) << 5));
            FMA32(v3, wt + ((c + 3) << 5));
        }
    }
    #undef FMA32

    float* __restrict__ ob = out + (size_t)b * COUT * HW_ + h * W_ + w;
    ob[ 0 * HW_] = fmaxf(s0, 0.0f);   ob[ 1 * HW_] = fmaxf(s1, 0.0f);
    ob[ 2 * HW_] = fmaxf(s2, 0.0f);   ob[ 3 * HW_] = fmaxf(s3, 0.0f);
    ob[ 4 * HW_] = fmaxf(s4, 0.0f);   ob[ 5 * HW_] = fmaxf(s5, 0.0f);
    ob[ 6 * HW_] = fmaxf(s6, 0.0f);   ob[ 7 * HW_] = fmaxf(s7, 0.0f);
    ob[ 8 * HW_] = fmaxf(s8, 0.0f);   ob[ 9 * HW_] = fmaxf(s9, 0.0f);
    ob[10 * HW_] = fmaxf(s10, 0.0f);  ob[11 * HW_] = fmaxf(s11, 0.0f);
    ob[12 * HW_] = fmaxf(s12, 0.0f);  ob[13 * HW_] = fmaxf(s13, 0.0f);
    ob[14 * HW_] = fmaxf(s14, 0.0f);  ob[15 * HW_] = fmaxf(s15, 0.0f);
    ob[16 * HW_] = fmaxf(s16, 0.0f);  ob[17 * HW_] = fmaxf(s17, 0.0f);
    ob[18 * HW_] = fmaxf(s18, 0.0f);  ob[19 * HW_] = fmaxf(s19, 0.0f);
    ob[20 * HW_] = fmaxf(s20, 0.0f);  ob[21 * HW_] = fmaxf(s21, 0.0f);
    ob[22 * HW_] = fmaxf(s22, 0.0f);  ob[23 * HW_] = fmaxf(s23, 0.0f);
    ob[24 * HW_] = fmaxf(s24, 0.0f);  ob[25 * HW_] = fmaxf(s25, 0.0f);
    ob[26 * HW_] = fmaxf(s26, 0.0f);  ob[27 * HW_] = fmaxf(s27, 0.0f);
    ob[28 * HW_] = fmaxf(s28, 0.0f);  ob[29 * HW_] = fmaxf(s29, 0.0f);
    ob[30 * HW_] = fmaxf(s30, 0.0f);  ob[31 * HW_] = fmaxf(s31, 0.0f);
}

extern "C" void kernel_launch(void* const* d_in, const int* in_sizes, int n_in,
                              void* d_out, int out_size, void* d_ws, size_t ws_size,
                              hipStream_t stream) {
    const float* x     = (const float*)d_in[0];
    const float* w_off = (const float*)d_in[1];
    const float* b_off = (const float*)d_in[2];
    const float* w_dcn = (const float*)d_in[3];
    float* out    = (float*)d_out;
    float* off_ws = (float*)d_ws;   // needs 18*204800*4 = 14.75 MB

    dcn_offset<<<800, 256, 0, stream>>>(x, w_off, b_off, off_ws);
    dcn_sample<<<800, 256, 0, stream>>>(x, w_dcn, off_ws, out);
}